// Round 10
// baseline (55.827 us; speedup 1.0000x reference)
//
#include <hip/hip_runtime.h>

#define F_BINS  257
#define T_STEPS 65536
#define N_ACT   256
#define TM      128           // t-columns per block (full 512B xs lines)
#define NBLK    512           // T_STEPS / TM
#define NTHR    512           // 8 waves
#define XO_CHUNK 8224         // float4 per block: 257*65536/4/512, exact

typedef float f32x4 __attribute__((ext_vector_type(4)));
typedef short s16x8 __attribute__((ext_vector_type(8)));
typedef unsigned u32x4 __attribute__((ext_vector_type(4)));
typedef unsigned long long u64;

// ws layout:
//   [0]      double Sc
//   [8]      double Sb
//   [16384]  unsigned maskp[NBLK*8]
//   [65536]  uchar Gfrag[147456]   (B frags, MFMA order: [kk][n][lane][16B])
#define WS_SC    0
#define WS_SB    8
#define WS_MASK  16384
#define WS_GFRAG 65536

__device__ __forceinline__ unsigned short f2bf_rne(float x) {
  unsigned u = __builtin_bit_cast(unsigned, x);
  return (unsigned short)((u + 0x7FFFu + ((u >> 16) & 1u)) >> 16);
}
// bf16(hi)<<16 | bf16(lo) by truncation: one v_perm_b32
__device__ __forceinline__ unsigned pack_bf(float hi, float lo) {
  return __builtin_amdgcn_perm(__builtin_bit_cast(unsigned, hi),
                               __builtin_bit_cast(unsigned, lo), 0x07060302u);
}
#define PACK8(v) __builtin_bit_cast(s16x8, (u32x4){                          \
      pack_bf((v)[1], (v)[0]), pack_bf((v)[3], (v)[2]),                      \
      pack_bf((v)[5], (v)[4]), pack_bf((v)[7], (v)[6])})
// monotonic float->u32 (order-preserving, finite inputs)
__device__ __forceinline__ unsigned mono(float v) {
  unsigned u = __builtin_bit_cast(unsigned, v);
  return u ^ (unsigned)(((int)u >> 31) | (int)0x80000000);
}

// ---------------------------------------------------------------------------
// B fragments in MFMA order:
// Gfrag[((kk*16+n)*64+lane)*16] = 8 bf16 of G[f=32kk+8(lane>>4)+j][a=16n+(lane&15)]
// ---------------------------------------------------------------------------
__global__ __launch_bounds__(256) void k_prep(const float* __restrict__ G,
                                              unsigned char* __restrict__ gfrag) {
  const int u = blockIdx.x * 256 + threadIdx.x;   // 0..9215
  const int lane = u & 63, ng = (u >> 6) & 15, kk = u >> 10;
  const int r16 = lane & 15, g = lane >> 4;
  const int a = ng * 16 + r16;
  unsigned short h[8];
#pragma unroll
  for (int j = 0; j < 8; ++j) {
    const int f = kk * 32 + 8 * g + j;
    h[j] = (f < F_BINS) ? f2bf_rne(G[f * N_ACT + a]) : (unsigned short)0;
  }
  u32x4 w;
#pragma unroll
  for (int i = 0; i < 4; ++i)
    w[i] = (unsigned)h[2 * i] | ((unsigned)h[2 * i + 1] << 16);
  *(u32x4*)(gfrag + (size_t)u * 16) = w;
}

// ---------------------------------------------------------------------------
// GEMM+argmax+xo^2. 512 thr / 8 waves. Wave (tq, ah): t in [t0+32tq, +32),
// actions [128ah, +128). ALL of B (144KiB) staged to LDS once; then the
// K-loop is sync-free: pack va[kk%3] (implicit counted vmcnt), issue A-slot
// kk+3, 8 ds_read_b128, 16 MFMA. Action halves merged via LDS u64 keys.
// ---------------------------------------------------------------------------
__global__ __launch_bounds__(NTHR, 2) void k_gemm(
    const float* __restrict__ xs, const float* __restrict__ xo,
    const unsigned char* __restrict__ gfrag,
    unsigned* __restrict__ maskp, double* __restrict__ Sb) {
  const int tid = threadIdx.x, lane = tid & 63, wv = tid >> 6;
  const int tq = wv & 3, ah = wv >> 2;
  const int g = lane >> 4, r16 = lane & 15;
  const int t0 = blockIdx.x * TM;
  const int trow = t0 + 32 * tq + r16;   // tau=0 row; tau=1 is +16

  __shared__ __align__(16) unsigned char Bb[147456];  // all 9 B kk-slices
  __shared__ u64 mbuf[2][TM];
  __shared__ unsigned lmask[8];
  __shared__ double sdw[8];
  if (tid < 8) lmask[tid] = 0u;

  // ---- stage ALL of B: 144 x 1KB chunks; wave wv does [18wv, 18wv+18) ----
#pragma unroll
  for (int i = 0; i < 18; ++i) {
    const int c = 18 * wv + i;
    const unsigned char* src = gfrag + (size_t)c * 1024 + (size_t)lane * 16;
    unsigned char* dst = &Bb[c * 1024];
    __builtin_amdgcn_global_load_lds(
        (const __attribute__((address_space(1))) unsigned*)src,
        (__attribute__((address_space(3))) unsigned*)dst, 16, 0, 0);
  }
  __builtin_amdgcn_sched_barrier(0);   // pin: B-stage issued before A-prologue

  // A: 16 dwords into slot s (2 tau x 8 f); f-run 8g..8g+7 at fixed t
#define LOAD_A(s, kkv)                                                        \
  {                                                                           \
    _Pragma("unroll") for (int tau = 0; tau < 2; ++tau)                       \
    _Pragma("unroll") for (int j = 0; j < 8; ++j) {                           \
      int f = 32 * (kkv) + 8 * g + j;                                         \
      if ((kkv) == 8) f = f > 256 ? 256 : f; /* Gfrag zero rows cover pad */  \
      va[s][tau][j] = xs[(size_t)f * T_STEPS + trow + 16 * tau];              \
    }                                                                         \
  }

  float va[3][2][8];
  LOAD_A(0, 0) LOAD_A(1, 1) LOAD_A(2, 2)
  __builtin_amdgcn_sched_barrier(0);   // pin: prologue issued before the wait
  asm volatile("s_waitcnt vmcnt(48)" ::: "memory");  // B staged; A in flight
  __builtin_amdgcn_s_barrier();        // all waves' B portions visible

  f32x4 acc[2][8];                     // [tau][n], actions 128ah+16n+r16
#pragma unroll
  for (int tau = 0; tau < 2; ++tau)
#pragma unroll
    for (int n = 0; n < 8; ++n) acc[tau][n] = (f32x4){0.f, 0.f, 0.f, 0.f};

#pragma unroll
  for (int kk = 0; kk < 9; ++kk) {
    const int s = kk % 3;
    // implicit compiler vmcnt(32) here: waits slot s only (2 slots younger)
    const s16x8 af0 = PACK8(va[s][0]);
    const s16x8 af1 = PACK8(va[s][1]);
    if (kk + 3 <= 8) LOAD_A(s, kk + 3)
    const unsigned char* bp = &Bb[((kk * 16 + 8 * ah) * 64 + lane) * 16];
#pragma unroll
    for (int n = 0; n < 8; ++n) {
      const s16x8 bfr = *(const s16x8*)(bp + n * 1024);
      acc[0][n] = __builtin_amdgcn_mfma_f32_16x16x32_bf16(af0, bfr, acc[0][n], 0, 0, 0);
      acc[1][n] = __builtin_amdgcn_mfma_f32_16x16x32_bf16(af1, bfr, acc[1][n], 0, 0, 0);
    }
  }
#undef LOAD_A

  // ---- argmax per row t = t0+32tq+16tau+4g+q over this wave's 128 a ----
#pragma unroll
  for (int tau = 0; tau < 2; ++tau) {
#pragma unroll
    for (int q = 0; q < 4; ++q) {
      float bv = acc[tau][0][q];
      int   bc = 128 * ah + r16;
#pragma unroll
      for (int n = 1; n < 8; ++n) {
        const int c = 128 * ah + 16 * n + r16;
        if (acc[tau][n][q] > bv) { bv = acc[tau][n][q]; bc = c; }
      }
#pragma unroll
      for (int m = 1; m <= 8; m <<= 1) {   // reduce over r16 (bits 0..3)
        const float ov = __shfl_xor(bv, m);
        const int   oc = __shfl_xor(bc, m);
        if (ov > bv || (ov == bv && oc < bc)) { bv = ov; bc = oc; }
      }
      if (r16 == 0)
        mbuf[ah][32 * tq + 16 * tau + 4 * g + q] =
            ((u64)mono(bv) << 32) | (unsigned)(~bc);
    }
  }
  __syncthreads();
  if (tid < TM) {
    const u64 k0 = mbuf[0][tid], k1 = mbuf[1][tid];
    const u64 k = k0 > k1 ? k0 : k1;
    const unsigned bc = ~(unsigned)(k & 0xFFFFFFFFull);
    atomicOr(&lmask[bc >> 5], 1u << (bc & 31));
  }
  __syncthreads();
  if (tid < 8) maskp[blockIdx.x * 8 + tid] = lmask[tid];

  // ---- fused sum of x_out^2: contiguous per-block float4 chunk ----
  const float4* xo4 = (const float4*)xo;
  const size_t base = (size_t)blockIdx.x * XO_CHUNK;
  double ds = 0.0;
#pragma unroll 8
  for (int i = tid; i < XO_CHUNK; i += NTHR) {
    const float4 v = xo4[base + i];
    ds += (double)fmaf(v.x, v.x, v.y * v.y) + (double)fmaf(v.z, v.z, v.w * v.w);
  }
#pragma unroll
  for (int off = 32; off; off >>= 1) ds += __shfl_down(ds, off);
  if (lane == 0) sdw[wv] = ds;
  __syncthreads();
  if (tid == 0) {
    double s = 0.0;
#pragma unroll
    for (int w = 0; w < 8; ++w) s += sdw[w];
    atomicAdd(Sb, s);
  }
}

// ---------------------------------------------------------------------------
// OR-reduce per-block masks, then correction for selected columns t = a:
//   Sc += sum_f (G*xs)^2 - 2*(G*xs)*xo
// ---------------------------------------------------------------------------
__global__ __launch_bounds__(256) void k_corr(
    const float* __restrict__ xs, const float* __restrict__ xo,
    const float* __restrict__ G, const unsigned* __restrict__ maskp,
    double* __restrict__ Sc) {
  __shared__ unsigned m8[8];
  const int tid = threadIdx.x;
  if (tid < 8) m8[tid] = 0u;
  __syncthreads();
  unsigned m = 0;
  for (int b = tid >> 3; b < NBLK; b += 32) m |= maskp[b * 8 + (tid & 7)];
  atomicOr(&m8[tid & 7], m);
  __syncthreads();
  const int f = blockIdx.x, a = tid;
  const bool sel = (m8[a >> 5] >> (a & 31)) & 1u;
  const float gv  = G[f * N_ACT + a];
  const float xsv = xs[(size_t)f * T_STEPS + a];
  const float xov = xo[(size_t)f * T_STEPS + a];
  const float gx  = gv * xsv;
  double acc = sel ? (double)(gx * (gx - 2.f * xov)) : 0.0;
#pragma unroll
  for (int off = 32; off; off >>= 1) acc += __shfl_down(acc, off);
  __shared__ double sdc[4];
  if ((tid & 63) == 0) sdc[tid >> 6] = acc;
  __syncthreads();
  if (tid == 0) atomicAdd(Sc, sdc[0] + sdc[1] + sdc[2] + sdc[3]);
}

__global__ void k_final(const double* __restrict__ Sb,
                        const double* __restrict__ Sc,
                        float* __restrict__ out) {
  out[0] = (float)((Sb[0] + Sc[0]) / ((double)F_BINS * (double)T_STEPS));
}

extern "C" void kernel_launch(void* const* d_in, const int* in_sizes, int n_in,
                              void* d_out, int out_size, void* d_ws, size_t ws_size,
                              hipStream_t stream) {
  const float* x_out    = (const float*)d_in[0];
  const float* x_source = (const float*)d_in[1];
  // d_in[2] (x_clean) is dead: argmin_a(clean_sum - proj) == argmax_a proj
  const float* G        = (const float*)d_in[3];

  char* ws = (char*)d_ws;
  double*        Sc    = (double*)(ws + WS_SC);
  double*        Sb    = (double*)(ws + WS_SB);
  unsigned*      maskp = (unsigned*)(ws + WS_MASK);
  unsigned char* gfrag = (unsigned char*)(ws + WS_GFRAG);

  hipMemsetAsync(d_ws, 0, 64, stream);   // Sc, Sb
  k_prep <<<36, 256, 0, stream>>>(G, gfrag);
  k_gemm <<<NBLK, NTHR, 0, stream>>>(x_source, x_out, gfrag, maskp, Sb);
  k_corr <<<F_BINS, 256, 0, stream>>>(x_source, x_out, G, maskp, Sc);
  k_final<<<1, 1, 0, stream>>>(Sb, Sc, (float*)d_out);
}